// Round 3
// baseline (448.371 us; speedup 1.0000x reference)
//
#include <hip/hip_runtime.h>
#include <math.h>

namespace {
constexpr int N_TOK  = 8192;
constexpr int GROUPS = 4;
constexpr int D      = 128;
} // namespace

typedef short v8s __attribute__((ext_vector_type(8)));
typedef float v4f __attribute__((ext_vector_type(4)));

typedef const __attribute__((address_space(1))) unsigned g_u32;
typedef __attribute__((address_space(3))) unsigned l_u32;

__device__ __forceinline__ short f2bf(float f) {
    union { float f; unsigned u; } x; x.f = f;
    unsigned r = x.u + 0x7FFFu + ((x.u >> 16) & 1u);
    return (short)(r >> 16);
}

// ---------------------------------------------------------------------------
// Build M^T [128 cols][1024 k] bf16 in workspace.  (unchanged — ~5 us)
// ---------------------------------------------------------------------------
__global__ __launch_bounds__(256)
void build_MT(const float* __restrict__ widx,  // [32][16][16]
              const float* __restrict__ wn,    // [64][960]
              short* __restrict__ MT)          // [128][1024]
{
    const int idx = blockIdx.x * 256 + threadIdx.x;   // 131072 total
    const int col = idx >> 10;
    const int kk  = idx & 1023;
    const int g   = kk >> 7;
    const int dp  = kk & 127;
    const int part = dp >> 6;
    const int dpp  = dp & 63;
    const int B    = (dpp & 1) * 16 + (dpp >> 2);
    const int c    = g + 8 * ((dpp >> 1) & 1);

    float val;
    if (col < 64) {
        val = (col == part * 32 + B) ? widx[B * 256 + c * 16] : 0.f;
    } else {
        const int d2 = col - 64;
        const float* wrow = wn + d2 * 960 + part * 480 + B * 15;
        const float* wi   = widx + B * 256 + c * 16;
        float s = 0.f;
#pragma unroll
        for (int o = 1; o < 16; ++o) s += wi[o] * wrow[o - 1];
        val = s;
    }
    MT[idx] = f2bf(val);
}

// ---------------------------------------------------------------------------
// Main GEMM: Out[40960][128] = A[40960][1024] x M[1024][128]
// Rope/nope column split (blockIdx bit0) as before. NEW: A streamed through
// LDS via global_load_lds (width 16) in 16 chunks of BK=64 (16 KB f32 each),
// double-buffered (32 KB -> 5 blocks/CU = 160 KB LDS, 20 waves/CU).
// T3 minimum-2-phase: STAGE(c+1) || compute(c) -> __syncthreads (vmcnt drain).
// In-flight bytes now live in LDS (16 KB/block staged/step), not VGPRs.
// Bank-conflict fix (rule #21 both-sides swizzle): slot s of row r stored at
// s ^ (r&15) via pre-swizzled per-lane GLOBAL source addr; ds_read applies
// the same XOR -> even 8-words/bank distribution (~12 cy/b128).
// ---------------------------------------------------------------------------
__global__ __launch_bounds__(256, 5)
void gemm_kernel(const float* __restrict__ q,       // [N,32,128]
                 const float* __restrict__ k,       // [N,8,128]
                 const float* __restrict__ q_orig,  // [N,32,128]
                 const float* __restrict__ k_orig,  // [N,8,128]
                 const short* __restrict__ MT,      // [128][1024] bf16
                 float* __restrict__ out_iq,        // [N,4,128]
                 float* __restrict__ out_ik)        // [N,128]
{
    __shared__ float lds[2][4096];                  // 2 x 16 KB

    const int lane = threadIdx.x & 63;
    const int wave = threadIdx.x >> 6;
    const int m    = lane & 15;
    const int quad = lane >> 4;
    const int half = blockIdx.x & 1;                // 0 = rope, 1 = nope
    const int base_row = (blockIdx.x >> 1) * 64 + wave * 16;

    const float* qsrc = half ? q_orig : q;
    const float* ksrc = half ? k_orig : k;

    // Staging: wave stages its own 16 rows; call j covers rows j*4+(lane>>4),
    // lane provides 16B slot (lane&15), pre-XORed with (row&15).
    const float* gp[4];
    int isq_[4];
#pragma unroll
    for (int j = 0; j < 4; ++j) {
        const int r  = base_row + j * 4 + (lane >> 4);
        const int n  = r / 5;
        const int jj = r - n * 5;
        const int sx = (lane & 15) ^ (r & 15);      // source pre-swizzle
        if (jj < 4) { isq_[j] = 1; gp[j] = qsrc + n * 4096 + jj * 128 + sx * 4; }
        else        { isq_[j] = 0; gp[j] = ksrc + n * 1024 + sx * 4; }
    }

    const short* bbase = MT + (half * 64 + m) * 1024;

    v4f acc[4];
#pragma unroll
    for (int t = 0; t < 4; ++t) acc[t] = (v4f){0.f, 0.f, 0.f, 0.f};

    auto stage = [&](int c, int buf) {
        const int qoff = (c >> 1) * 512 + (c & 1) * 64;
        const int koff = c * 64;
#pragma unroll
        for (int j = 0; j < 4; ++j) {
            const float* g = gp[j] + (isq_[j] ? qoff : koff);
            __builtin_amdgcn_global_load_lds(
                (g_u32*)g,
                (l_u32*)&lds[buf][(wave * 4 + j) * 256],
                16, 0, 0);
        }
    };

    stage(0, 0);
    __syncthreads();                                // buf0 ready (vmcnt drain)

#pragma unroll 2
    for (int c = 0; c < 16; ++c) {
        const int buf = c & 1;
        if (c < 15) stage(c + 1, buf ^ 1);          // issue next chunk early

        const float* Ab = &lds[buf][(wave * 16 + m) * 64];
#pragma unroll
        for (int ks2 = 0; ks2 < 2; ++ks2) {
            const int s0 = ks2 * 8 + quad * 2;
            const float4 a0 = *(const float4*)(Ab + (((s0    ) ^ m) << 2));
            const float4 a1 = *(const float4*)(Ab + (((s0 + 1) ^ m) << 2));
            v8s a;
            a[0] = f2bf(a0.x); a[1] = f2bf(a0.y); a[2] = f2bf(a0.z); a[3] = f2bf(a0.w);
            a[4] = f2bf(a1.x); a[5] = f2bf(a1.y); a[6] = f2bf(a1.z); a[7] = f2bf(a1.w);

            const short* bp = bbase + c * 64 + ks2 * 32 + quad * 8;
#pragma unroll
            for (int t = 0; t < 4; ++t) {
                const v8s b = *(const v8s*)(bp + t * 16384);  // t*16 cols * 1024
                acc[t] = __builtin_amdgcn_mfma_f32_16x16x32_bf16(a, b, acc[t], 0, 0, 0);
            }
        }
        __syncthreads();   // drains stage(c+1) loads; next iter reads buf^1
    }

    // C/D layout: col = lane&15, row_in_tile = quad*4 + reg
#pragma unroll
    for (int t = 0; t < 4; ++t) {
        const int col = half * 64 + t * 16 + m;
#pragma unroll
        for (int i = 0; i < 4; ++i) {
            const int r2  = base_row + quad * 4 + i;
            const int n2  = r2 / 5;
            const int jj2 = r2 - n2 * 5;
            float* dst = (jj2 < 4) ? (out_iq + n2 * 512 + jj2 * 128)
                                   : (out_ik + n2 * 128);
            dst[col] = acc[t][i];
        }
    }
}

// ---------------------------------------------------------------------------
// Weights (unchanged from round 2 — passed, presumed ~15-30 us).
// ---------------------------------------------------------------------------
__global__ __launch_bounds__(512)
void weights_kernel(const float* __restrict__ v,    // [N,8,128]
                    const float* __restrict__ vt,   // [32,128,4]
                    float* __restrict__ out_w)      // [N,4]
{
    __shared__ float4 s_vt[4096];                    // 64 KB, reused for reduce
    const int tid = threadIdx.x;

    const float4* vt4 = (const float4*)vt;
#pragma unroll
    for (int i0 = 0; i0 < 8; ++i0) {
        const int i   = i0 * 512 + tid;
        const int hh  = i >> 7;
        const int low = i & 127;
        s_vt[(i & ~127) | (low ^ (hh & 7))] = vt4[i];
    }
    __syncthreads();

    const int tok_l = tid & 15;        // 0..15
    const int h     = tid >> 4;        // 0..31
    const int g     = h >> 2;
    const int sw    = h & 7;
    const int token = blockIdx.x * 16 + tok_l;

    const float4* vrow = (const float4*)(v + token * 1024 + g * 128);
    const float4* wrow = s_vt + h * 128;

    float ax = 0.f, ay = 0.f, az = 0.f, aw = 0.f;
#pragma unroll 8
    for (int d4 = 0; d4 < 32; ++d4) {
        const float4 vv = vrow[d4];
        {
            const float4 w0 = wrow[(d4 * 4 + 0) ^ sw];
            ax += vv.x * w0.x; ay += vv.x * w0.y; az += vv.x * w0.z; aw += vv.x * w0.w;
        }
        {
            const float4 w1 = wrow[(d4 * 4 + 1) ^ sw];
            ax += vv.y * w1.x; ay += vv.y * w1.y; az += vv.y * w1.z; aw += vv.y * w1.w;
        }
        {
            const float4 w2 = wrow[(d4 * 4 + 2) ^ sw];
            ax += vv.z * w2.x; ay += vv.z * w2.y; az += vv.z * w2.z; aw += vv.z * w2.w;
        }
        {
            const float4 w3 = wrow[(d4 * 4 + 3) ^ sw];
            ax += vv.w * w3.x; ay += vv.w * w3.y; az += vv.w * w3.z; aw += vv.w * w3.w;
        }
    }
    const float s = ax * ax + ay * ay + az * az + aw * aw;

    __syncthreads();                    // all s_vt reads done
    float* s_red = (float*)s_vt;
    s_red[tok_l * 32 + h] = s;          // layout [tok][h = g*4+j]
    __syncthreads();
    if (tid < 64) {
        const int tok = tid & 15;
        const int j   = tid >> 4;       // 0..3
        const float* p = s_red + tok * 32 + j;
        float t = 0.f;
#pragma unroll
        for (int g2 = 0; g2 < 8; ++g2) t += p[g2 * 4];
        out_w[(blockIdx.x * 16 + tok) * 4 + j] = sqrtf(t);
    }
}

extern "C" void kernel_launch(void* const* d_in, const int* in_sizes, int n_in,
                              void* d_out, int out_size, void* d_ws, size_t ws_size,
                              hipStream_t stream) {
    const float* q      = (const float*)d_in[0];
    const float* k      = (const float*)d_in[1];
    const float* v      = (const float*)d_in[2];
    const float* q_orig = (const float*)d_in[3];
    const float* k_orig = (const float*)d_in[4];
    const float* widx   = (const float*)d_in[5];
    const float* wn     = (const float*)d_in[6];
    const float* vt     = (const float*)d_in[7];

    float* out_iq = (float*)d_out;
    float* out_ik = out_iq + (size_t)N_TOK * GROUPS * D;  // +4,194,304
    float* out_w  = out_ik + (size_t)N_TOK * D;           // +1,048,576

    short* MT = (short*)d_ws;  // 128*1024 bf16 = 256 KB

    hipLaunchKernelGGL(build_MT, dim3(512), dim3(256), 0, stream, widx, wn, MT);
    hipLaunchKernelGGL(gemm_kernel, dim3(1280), dim3(256), 0, stream,
                       q, k, q_orig, k_orig, MT, out_iq, out_ik);
    hipLaunchKernelGGL(weights_kernel, dim3(512), dim3(512), 0, stream,
                       v, vt, out_w);
}

// Round 5
// 409.757 us; speedup vs baseline: 1.0942x; 1.0942x over previous
//
#include <hip/hip_runtime.h>
#include <math.h>

namespace {
constexpr int N_TOK  = 8192;
constexpr int GROUPS = 4;
constexpr int D      = 128;
} // namespace

typedef short v8s __attribute__((ext_vector_type(8)));
typedef float v4f __attribute__((ext_vector_type(4)));

__device__ __forceinline__ short f2bf(float f) {
    union { float f; unsigned u; } x; x.f = f;
    unsigned r = x.u + 0x7FFFu + ((x.u >> 16) & 1u);
    return (short)(r >> 16);
}

// ---------------------------------------------------------------------------
// Build M^T [128 cols][1024 k] bf16 in workspace.  (unchanged — ~10 us)
// ---------------------------------------------------------------------------
__global__ __launch_bounds__(256)
void build_MT(const float* __restrict__ widx,  // [32][16][16]
              const float* __restrict__ wn,    // [64][960]
              short* __restrict__ MT)          // [128][1024]
{
    const int idx = blockIdx.x * 256 + threadIdx.x;   // 131072 total
    const int col = idx >> 10;
    const int kk  = idx & 1023;
    const int g   = kk >> 7;
    const int dp  = kk & 127;
    const int part = dp >> 6;
    const int dpp  = dp & 63;
    const int B    = (dpp & 1) * 16 + (dpp >> 2);
    const int c    = g + 8 * ((dpp >> 1) & 1);

    float val;
    if (col < 64) {
        val = (col == part * 32 + B) ? widx[B * 256 + c * 16] : 0.f;
    } else {
        const int d2 = col - 64;
        const float* wrow = wn + d2 * 960 + part * 480 + B * 15;
        const float* wi   = widx + B * 256 + c * 16;
        float s = 0.f;
#pragma unroll
        for (int o = 1; o < 16; ++o) s += wi[o] * wrow[o - 1];
        val = s;
    }
    MT[idx] = f2bf(val);
}

// ---------------------------------------------------------------------------
// Main GEMM: Out[40960][128] = A[40960][1024] x M[1024][128]
// Rope/nope column split (blockIdx bit0): rope blocks read q/k, nope blocks
// read q_orig/k_orig -> 2x waves at identical HBM traffic (proven r2).
// r4: explicit depth-4 register pipeline for A. Named v4f slots (clang
// ext_vector -> valid for __builtin_nontemporal_load; no runtime-indexed
// arrays -> no scratch), fully-unrolled 8-step loop, each step consumes
// 4 k-iters and reissues their slots for iter+4. Load->use distance =
// 4 iters (~8 wave-loads in flight per wave). A loads nontemporal
// (zero reuse; keep L1 for MT/B).
// ---------------------------------------------------------------------------
#define NTL(p) __builtin_nontemporal_load((const v4f*)(p))

__global__ __launch_bounds__(256, 4)
void gemm_kernel(const float* __restrict__ q,       // [N,32,128]
                 const float* __restrict__ k,       // [N,8,128]
                 const float* __restrict__ q_orig,  // [N,32,128]
                 const float* __restrict__ k_orig,  // [N,8,128]
                 const short* __restrict__ MT,      // [128][1024] bf16
                 float* __restrict__ out_iq,        // [N,4,128]
                 float* __restrict__ out_ik)        // [N,128]
{
    const int lane = threadIdx.x & 63;
    const int wave = threadIdx.x >> 6;
    const int m    = lane & 15;
    const int quad = lane >> 4;
    const int half = blockIdx.x & 1;                   // 0 = rope, 1 = nope
    const int base_row = (blockIdx.x >> 1) * 64 + wave * 16;

    // per-lane A row
    const int row = base_row + m;
    const int n   = row / 5;
    const int jj  = row - n * 5;
    const bool isq = (jj < 4);
    const float* ap;
    if (half == 0) ap = isq ? (q      + n * 4096 + jj * 128) : (k      + n * 1024);
    else           ap = isq ? (q_orig + n * 4096 + jj * 128) : (k_orig + n * 1024);
    const float* apq = ap + quad * 8;     // +quad's 8-float sub-chunk
    const int s4 = isq ? 512 : 128;       // A advance per 4 k-iters

    const short* bq = MT + (half * 64 + m) * 1024 + quad * 8;

    v4f acc[4];
#pragma unroll
    for (int t = 0; t < 4; ++t) acc[t] = (v4f){0.f, 0.f, 0.f, 0.f};

    // ---- prologue: load iters 0..3 into named slots ----
    v4f a0x = NTL(apq +  0), a0y = NTL(apq +   4);
    v4f a1x = NTL(apq + 32), a1y = NTL(apq +  36);
    v4f a2x = NTL(apq + 64), a2y = NTL(apq +  68);
    v4f a3x = NTL(apq + 96), a3y = NTL(apq + 100);

#define SLOT(AX, AY, J)                                                        \
    {                                                                          \
        v8s a;                                                                 \
        a[0] = f2bf(AX.x); a[1] = f2bf(AX.y); a[2] = f2bf(AX.z); a[3] = f2bf(AX.w); \
        a[4] = f2bf(AY.x); a[5] = f2bf(AY.y); a[6] = f2bf(AY.z); a[7] = f2bf(AY.w); \
        if (s < 7) { AX = NTL(nxt + (J) * 32); AY = NTL(nxt + (J) * 32 + 4); } \
        const short* bp = bs + (J) * 32;                                       \
        _Pragma("unroll")                                                      \
        for (int t = 0; t < 4; ++t) {                                          \
            const v8s b = *(const v8s*)(bp + t * 16384);                       \
            acc[t] = __builtin_amdgcn_mfma_f32_16x16x32_bf16(a, b, acc[t], 0, 0, 0); \
        }                                                                      \
    }

#pragma unroll
    for (int s = 0; s < 8; ++s) {        // k-iters s*4 .. s*4+3
        const float* nxt = apq + (s + 1) * s4;
        const short* bs  = bq + s * 128;
        SLOT(a0x, a0y, 0)
        SLOT(a1x, a1y, 1)
        SLOT(a2x, a2y, 2)
        SLOT(a3x, a3y, 3)
    }
#undef SLOT

    // C/D layout: col = lane&15, row_in_tile = quad*4 + reg
#pragma unroll
    for (int t = 0; t < 4; ++t) {
        const int col = half * 64 + t * 16 + m;
#pragma unroll
        for (int i = 0; i < 4; ++i) {
            const int r2  = base_row + quad * 4 + i;
            const int n2  = r2 / 5;
            const int jj2 = r2 - n2 * 5;
            float* dst = (jj2 < 4) ? (out_iq + n2 * 512 + jj2 * 128)
                                   : (out_ik + n2 * 128);
            dst[col] = acc[t][i];
        }
    }
}

// ---------------------------------------------------------------------------
// Weights (unchanged from round 2 — passed; LDS-staged vt, float4 loads).
// ---------------------------------------------------------------------------
__global__ __launch_bounds__(512)
void weights_kernel(const float* __restrict__ v,    // [N,8,128]
                    const float* __restrict__ vt,   // [32,128,4]
                    float* __restrict__ out_w)      // [N,4]
{
    __shared__ float4 s_vt[4096];                    // 64 KB, reused for reduce
    const int tid = threadIdx.x;

    const float4* vt4 = (const float4*)vt;
#pragma unroll
    for (int i0 = 0; i0 < 8; ++i0) {
        const int i   = i0 * 512 + tid;
        const int hh  = i >> 7;
        const int low = i & 127;
        s_vt[(i & ~127) | (low ^ (hh & 7))] = vt4[i];
    }
    __syncthreads();

    const int tok_l = tid & 15;        // 0..15
    const int h     = tid >> 4;        // 0..31
    const int g     = h >> 2;
    const int sw    = h & 7;
    const int token = blockIdx.x * 16 + tok_l;

    const float4* vrow = (const float4*)(v + token * 1024 + g * 128);
    const float4* wrow = s_vt + h * 128;

    float ax = 0.f, ay = 0.f, az = 0.f, aw = 0.f;
#pragma unroll 8
    for (int d4 = 0; d4 < 32; ++d4) {
        const float4 vv = vrow[d4];
        {
            const float4 w0 = wrow[(d4 * 4 + 0) ^ sw];
            ax += vv.x * w0.x; ay += vv.x * w0.y; az += vv.x * w0.z; aw += vv.x * w0.w;
        }
        {
            const float4 w1 = wrow[(d4 * 4 + 1) ^ sw];
            ax += vv.y * w1.x; ay += vv.y * w1.y; az += vv.y * w1.z; aw += vv.y * w1.w;
        }
        {
            const float4 w2 = wrow[(d4 * 4 + 2) ^ sw];
            ax += vv.z * w2.x; ay += vv.z * w2.y; az += vv.z * w2.z; aw += vv.z * w2.w;
        }
        {
            const float4 w3 = wrow[(d4 * 4 + 3) ^ sw];
            ax += vv.w * w3.x; ay += vv.w * w3.y; az += vv.w * w3.z; aw += vv.w * w3.w;
        }
    }
    const float s = ax * ax + ay * ay + az * az + aw * aw;

    __syncthreads();                    // all s_vt reads done
    float* s_red = (float*)s_vt;
    s_red[tok_l * 32 + h] = s;          // layout [tok][h = g*4+j]
    __syncthreads();
    if (tid < 64) {
        const int tok = tid & 15;
        const int j   = tid >> 4;       // 0..3
        const float* p = s_red + tok * 32 + j;
        float t = 0.f;
#pragma unroll
        for (int g2 = 0; g2 < 8; ++g2) t += p[g2 * 4];
        out_w[(blockIdx.x * 16 + tok) * 4 + j] = sqrtf(t);
    }
}

extern "C" void kernel_launch(void* const* d_in, const int* in_sizes, int n_in,
                              void* d_out, int out_size, void* d_ws, size_t ws_size,
                              hipStream_t stream) {
    const float* q      = (const float*)d_in[0];
    const float* k      = (const float*)d_in[1];
    const float* v      = (const float*)d_in[2];
    const float* q_orig = (const float*)d_in[3];
    const float* k_orig = (const float*)d_in[4];
    const float* widx   = (const float*)d_in[5];
    const float* wn     = (const float*)d_in[6];
    const float* vt     = (const float*)d_in[7];

    float* out_iq = (float*)d_out;
    float* out_ik = out_iq + (size_t)N_TOK * GROUPS * D;  // +4,194,304
    float* out_w  = out_ik + (size_t)N_TOK * D;           // +1,048,576

    short* MT = (short*)d_ws;  // 128*1024 bf16 = 256 KB

    hipLaunchKernelGGL(build_MT, dim3(512), dim3(256), 0, stream, widx, wn, MT);
    hipLaunchKernelGGL(gemm_kernel, dim3(1280), dim3(256), 0, stream,
                       q, k, q_orig, k_orig, MT, out_iq, out_ik);
    hipLaunchKernelGGL(weights_kernel, dim3(4096 / 8, 1, 1), dim3(512), 0, stream,
                       v, vt, out_w);
}

// Round 6
// 382.012 us; speedup vs baseline: 1.1737x; 1.0726x over previous
//
#include <hip/hip_runtime.h>
#include <math.h>

namespace {
constexpr int N_TOK  = 8192;
constexpr int GROUPS = 4;
constexpr int D      = 128;
} // namespace

typedef short v8s __attribute__((ext_vector_type(8)));
typedef float v4f __attribute__((ext_vector_type(4)));

__device__ __forceinline__ short f2bf(float f) {
    union { float f; unsigned u; } x; x.f = f;
    unsigned r = x.u + 0x7FFFu + ((x.u >> 16) & 1u);
    return (short)(r >> 16);
}

// ---------------------------------------------------------------------------
// Build swizzled M^T in workspace, fragment-major so gemm B-loads are
// lane-contiguous:  MTsw[half][t][ks][lane=qd*16+mm][j]  (shorts)
//   col = half*64 + t*16 + mm,  k = ks*32 + qd*8 + j
// Same data as the old [col][1024] layout — pure index permutation.
// ---------------------------------------------------------------------------
__global__ __launch_bounds__(256)
void build_MT(const float* __restrict__ widx,  // [32][16][16]
              const float* __restrict__ wn,    // [64][960]
              short* __restrict__ MT)          // 131072 shorts (256 KB)
{
    const int idx = blockIdx.x * 256 + threadIdx.x;   // 131072 total
    const int col = idx >> 10;
    const int kk  = idx & 1023;
    const int g   = kk >> 7;
    const int dp  = kk & 127;
    const int part = dp >> 6;
    const int dpp  = dp & 63;
    const int B    = (dpp & 1) * 16 + (dpp >> 2);
    const int c    = g + 8 * ((dpp >> 1) & 1);

    float val;
    if (col < 64) {
        val = (col == part * 32 + B) ? widx[B * 256 + c * 16] : 0.f;
    } else {
        const int d2 = col - 64;
        const float* wrow = wn + d2 * 960 + part * 480 + B * 15;
        const float* wi   = widx + B * 256 + c * 16;
        float s = 0.f;
#pragma unroll
        for (int o = 1; o < 16; ++o) s += wi[o] * wrow[o - 1];
        val = s;
    }

    // swizzled destination index
    const int hf = col >> 6;
    const int c2 = col & 63;
    const int t  = c2 >> 4;
    const int mm = c2 & 15;
    const int ks = kk >> 5;
    const int qd = (kk >> 3) & 3;
    const int j  = kk & 7;
    const int sidx = ((((hf * 4 + t) * 32 + ks) * 4 + qd) * 16 + mm) * 8 + j;
    MT[sidx] = f2bf(val);
}

// ---------------------------------------------------------------------------
// Main GEMM: Out[40960][128] = A[40960][1024] x M[1024][128]
// Rope/nope column split (blockIdx bit0, proven r2). Depth-4 named-register
// NT pipeline for A (r5). NEW (r6): MT stored fragment-major, so each B
// wave-load is contiguous 1 KB (base + lane*16B) — 16 segments instead of
// 64 scattered lines. Removes the vector-mem issue-pipe serialization that
// capped delivered BW at ~2.5 TB/s.
// ---------------------------------------------------------------------------
#define NTL(p) __builtin_nontemporal_load((const v4f*)(p))

__global__ __launch_bounds__(256, 4)
void gemm_kernel(const float* __restrict__ q,       // [N,32,128]
                 const float* __restrict__ k,       // [N,8,128]
                 const float* __restrict__ q_orig,  // [N,32,128]
                 const float* __restrict__ k_orig,  // [N,8,128]
                 const short* __restrict__ MT,      // swizzled, 131072 shorts
                 float* __restrict__ out_iq,        // [N,4,128]
                 float* __restrict__ out_ik)        // [N,128]
{
    const int lane = threadIdx.x & 63;
    const int wave = threadIdx.x >> 6;
    const int m    = lane & 15;
    const int quad = lane >> 4;
    const int half = blockIdx.x & 1;                   // 0 = rope, 1 = nope
    const int base_row = (blockIdx.x >> 1) * 64 + wave * 16;

    // per-lane A row
    const int row = base_row + m;
    const int n   = row / 5;
    const int jj  = row - n * 5;
    const bool isq = (jj < 4);
    const float* ap;
    if (half == 0) ap = isq ? (q      + n * 4096 + jj * 128) : (k      + n * 1024);
    else           ap = isq ? (q_orig + n * 4096 + jj * 128) : (k_orig + n * 1024);
    const float* apq = ap + quad * 8;     // +quad's 8-float sub-chunk
    const int s4 = isq ? 512 : 128;       // A advance per 4 k-iters

    // B fragments: lane-contiguous. offset = (half*4+t)*32*512 + ki*512 + lane*8
    const short* bq = MT + half * 65536 + lane * 8;

    v4f acc[4];
#pragma unroll
    for (int t = 0; t < 4; ++t) acc[t] = (v4f){0.f, 0.f, 0.f, 0.f};

    // ---- prologue: load iters 0..3 into named slots ----
    v4f a0x = NTL(apq +  0), a0y = NTL(apq +   4);
    v4f a1x = NTL(apq + 32), a1y = NTL(apq +  36);
    v4f a2x = NTL(apq + 64), a2y = NTL(apq +  68);
    v4f a3x = NTL(apq + 96), a3y = NTL(apq + 100);

#define SLOT(AX, AY, J)                                                        \
    {                                                                          \
        v8s a;                                                                 \
        a[0] = f2bf(AX.x); a[1] = f2bf(AX.y); a[2] = f2bf(AX.z); a[3] = f2bf(AX.w); \
        a[4] = f2bf(AY.x); a[5] = f2bf(AY.y); a[6] = f2bf(AY.z); a[7] = f2bf(AY.w); \
        if (s < 7) { AX = NTL(nxt + (J) * 32); AY = NTL(nxt + (J) * 32 + 4); } \
        const short* bp = bs + (J) * 512;                                      \
        _Pragma("unroll")                                                      \
        for (int t = 0; t < 4; ++t) {                                          \
            const v8s b = *(const v8s*)(bp + t * 16384);                       \
            acc[t] = __builtin_amdgcn_mfma_f32_16x16x32_bf16(a, b, acc[t], 0, 0, 0); \
        }                                                                      \
    }

#pragma unroll
    for (int s = 0; s < 8; ++s) {        // k-iters s*4 .. s*4+3
        const float* nxt = apq + (s + 1) * s4;
        const short* bs  = bq + s * 2048;       // 4 k-iters * 512 shorts
        SLOT(a0x, a0y, 0)
        SLOT(a1x, a1y, 1)
        SLOT(a2x, a2y, 2)
        SLOT(a3x, a3y, 3)
    }
#undef SLOT

    // C/D layout: col = lane&15, row_in_tile = quad*4 + reg
#pragma unroll
    for (int t = 0; t < 4; ++t) {
        const int col = half * 64 + t * 16 + m;
#pragma unroll
        for (int i = 0; i < 4; ++i) {
            const int r2  = base_row + quad * 4 + i;
            const int n2  = r2 / 5;
            const int jj2 = r2 - n2 * 5;
            float* dst = (jj2 < 4) ? (out_iq + n2 * 512 + jj2 * 128)
                                   : (out_ik + n2 * 128);
            dst[col] = acc[t][i];
        }
    }
}

// ---------------------------------------------------------------------------
// Weights (unchanged — passed; LDS-staged vt, float4 loads).
// ---------------------------------------------------------------------------
__global__ __launch_bounds__(512)
void weights_kernel(const float* __restrict__ v,    // [N,8,128]
                    const float* __restrict__ vt,   // [32,128,4]
                    float* __restrict__ out_w)      // [N,4]
{
    __shared__ float4 s_vt[4096];                    // 64 KB, reused for reduce
    const int tid = threadIdx.x;

    const float4* vt4 = (const float4*)vt;
#pragma unroll
    for (int i0 = 0; i0 < 8; ++i0) {
        const int i   = i0 * 512 + tid;
        const int hh  = i >> 7;
        const int low = i & 127;
        s_vt[(i & ~127) | (low ^ (hh & 7))] = vt4[i];
    }
    __syncthreads();

    const int tok_l = tid & 15;        // 0..15
    const int h     = tid >> 4;        // 0..31
    const int g     = h >> 2;
    const int sw    = h & 7;
    const int token = blockIdx.x * 16 + tok_l;

    const float4* vrow = (const float4*)(v + token * 1024 + g * 128);
    const float4* wrow = s_vt + h * 128;

    float ax = 0.f, ay = 0.f, az = 0.f, aw = 0.f;
#pragma unroll 8
    for (int d4 = 0; d4 < 32; ++d4) {
        const float4 vv = vrow[d4];
        {
            const float4 w0 = wrow[(d4 * 4 + 0) ^ sw];
            ax += vv.x * w0.x; ay += vv.x * w0.y; az += vv.x * w0.z; aw += vv.x * w0.w;
        }
        {
            const float4 w1 = wrow[(d4 * 4 + 1) ^ sw];
            ax += vv.y * w1.x; ay += vv.y * w1.y; az += vv.y * w1.z; aw += vv.y * w1.w;
        }
        {
            const float4 w2 = wrow[(d4 * 4 + 2) ^ sw];
            ax += vv.z * w2.x; ay += vv.z * w2.y; az += vv.z * w2.z; aw += vv.z * w2.w;
        }
        {
            const float4 w3 = wrow[(d4 * 4 + 3) ^ sw];
            ax += vv.w * w3.x; ay += vv.w * w3.y; az += vv.w * w3.z; aw += vv.w * w3.w;
        }
    }
    const float s = ax * ax + ay * ay + az * az + aw * aw;

    __syncthreads();                    // all s_vt reads done
    float* s_red = (float*)s_vt;
    s_red[tok_l * 32 + h] = s;          // layout [tok][h = g*4+j]
    __syncthreads();
    if (tid < 64) {
        const int tok = tid & 15;
        const int j   = tid >> 4;       // 0..3
        const float* p = s_red + tok * 32 + j;
        float t = 0.f;
#pragma unroll
        for (int g2 = 0; g2 < 8; ++g2) t += p[g2 * 4];
        out_w[(blockIdx.x * 16 + tok) * 4 + j] = sqrtf(t);
    }
}

extern "C" void kernel_launch(void* const* d_in, const int* in_sizes, int n_in,
                              void* d_out, int out_size, void* d_ws, size_t ws_size,
                              hipStream_t stream) {
    const float* q      = (const float*)d_in[0];
    const float* k      = (const float*)d_in[1];
    const float* v      = (const float*)d_in[2];
    const float* q_orig = (const float*)d_in[3];
    const float* k_orig = (const float*)d_in[4];
    const float* widx   = (const float*)d_in[5];
    const float* wn     = (const float*)d_in[6];
    const float* vt     = (const float*)d_in[7];

    float* out_iq = (float*)d_out;
    float* out_ik = out_iq + (size_t)N_TOK * GROUPS * D;  // +4,194,304
    float* out_w  = out_ik + (size_t)N_TOK * D;           // +1,048,576

    short* MT = (short*)d_ws;  // 131072 bf16 = 256 KB, fragment-major

    hipLaunchKernelGGL(build_MT, dim3(512), dim3(256), 0, stream, widx, wn, MT);
    hipLaunchKernelGGL(gemm_kernel, dim3(1280), dim3(256), 0, stream,
                       q, k, q_orig, k_orig, MT, out_iq, out_ik);
    hipLaunchKernelGGL(weights_kernel, dim3(512), dim3(512), 0, stream,
                       v, vt, out_w);
}